// Round 7
// baseline (456.870 us; speedup 1.0000x reference)
//
#include <hip/hip_runtime.h>
#include <hip/hip_cooperative_groups.h>

namespace cg = cooperative_groups;

#define NVERT 6890
#define NJNT  24
#define NBETA 10
#define NPOSE 207
#define NBATCH 512
#define KPAD 224          // 207 pose + 10 shape + 1 template + 6 zero
#define MROWS 20736       // 108 * 192 >= 20670
#define NVC (NVERT * 3)   // 20670
#define GRID 256          // 1 block/CU — cooperative co-residency trivially satisfied

typedef __attribute__((ext_vector_type(8))) short short8;
typedef __attribute__((ext_vector_type(4))) float floatx4;

__constant__ int c_par[NJNT]   = {-1,0,0,0,1,2,3,4,5,6,7,8,9,9,9,12,13,14,16,17,18,19,20,21};
__constant__ int c_depth[NJNT] = { 0,1,1,1,2,2,2,3,3,3,4,4,4,4,4,5,5,5,6,6,7,7,8,8};

static __device__ __forceinline__ unsigned short f2bf(float x) {
  union { float f; unsigned u; } v; v.f = x;
  unsigned r = (v.u + 0x7FFFu + ((v.u >> 16) & 1u)) >> 16;
  return (unsigned short)r;
}
static __device__ __forceinline__ float bf2f(unsigned short h) {
  union { unsigned u; float f; } v; v.u = (unsigned)h << 16;
  return v.f;
}

// ---------- Phase 1: jreg (blocks<72, single stage) + buildA/buildW ----------
static __device__ __forceinline__ void phase1(
    const float* __restrict__ Jr, const float* __restrict__ vtpl,
    const float* __restrict__ sd, const float* __restrict__ pdir,
    const float* __restrict__ wgt, float* __restrict__ wsJ,
    unsigned short* __restrict__ AT, unsigned short* __restrict__ W16,
    char* smem) {
  const int tid = threadIdx.x;
  const int bid = blockIdx.x;
  const int lane = tid & 63, wv = tid >> 6;
  if (bid < 72) {
    const int j = bid / 3, c = bid - j * 3;
    float acc[11];
    #pragma unroll
    for (int k = 0; k < 11; ++k) acc[k] = 0.f;
    for (int v = tid; v < NVERT; v += 256) {
      const float w = Jr[j * NVERT + v];
      acc[0] += w * vtpl[v * 3 + c];
      const float* s = sd + (size_t)v * 30 + c * 10;
      #pragma unroll
      for (int k = 0; k < 10; ++k) acc[1 + k] += w * s[k];
    }
    #pragma unroll
    for (int off = 32; off > 0; off >>= 1) {
      #pragma unroll
      for (int k = 0; k < 11; ++k) acc[k] += __shfl_down(acc[k], off, 64);
    }
    float* red = (float*)smem;   // [4][11]
    if (lane == 0) {
      #pragma unroll
      for (int k = 0; k < 11; ++k) red[wv * 11 + k] = acc[k];
    }
    __syncthreads();
    if (tid == 0) {
      #pragma unroll
      for (int k = 0; k < 11; ++k) {
        const float s = red[k] + red[11 + k] + red[22 + k] + red[33 + k];
        if (k == 0) wsJ[bid] = s;
        else        wsJ[72 + bid * 10 + (k - 1)] = s;
      }
    }
  }
  const int gid = bid * 256 + tid;
  const int gstride = gridDim.x * 256;
  for (int u = gid; u < MROWS * KPAD / 8; u += gstride) {     // buildA
    const int row = u / 28, k0 = (u - row * 28) * 8;
    short8 r;
    #pragma unroll
    for (int e = 0; e < 8; ++e) {
      const int k = k0 + e;
      float val = 0.f;
      if (row < NVC) {
        if (k < NPOSE)            val = pdir[(size_t)row * NPOSE + k];
        else if (k < NPOSE + 10)  val = sd[(size_t)row * 10 + (k - NPOSE)];
        else if (k == NPOSE + 10) val = vtpl[row];
      }
      r[e] = (short)f2bf(val);
    }
    *(short8*)(AT + (size_t)u * 8) = r;
  }
  for (int u = gid; u < 6912 * 64 / 8; u += gstride) {        // buildW
    const int v = u >> 3, c0 = (u & 7) * 8;
    short8 r;
    #pragma unroll
    for (int e = 0; e < 8; ++e) {
      const int c = c0 + e, j = c & 31;
      const float w = (v < NVERT && j < 24) ? wgt[(size_t)v * 24 + j] : 0.f;
      const unsigned short hi = f2bf(w);
      r[e] = (short)((c >> 5) ? f2bf(w - bf2f(hi)) : hi);
    }
    *(short8*)(W16 + (size_t)u * 8) = r;
  }
}

// ---------- Phase 2: chain (blocks<128, wave=batch, tree-level parallel) ----------
static __device__ __forceinline__ void phase2(
    const float* __restrict__ betas, const float* __restrict__ thetas,
    const float* __restrict__ scale, const float* __restrict__ trans,
    const float* __restrict__ wsJ,
    unsigned short* __restrict__ BT, unsigned short* __restrict__ G16,
    char* smem) {
  if (blockIdx.x >= NBATCH / 4) return;
  float* sJ  = (float*)smem;                               // 792 f
  float* sJJ = (float*)(smem + 3168);                      // 4*72 f
  float* sM  = (float*)(smem + 4320);                      // 4*288 f
  unsigned short* sGc = (unsigned short*)(smem + 8928);    // 4*1024 us
  unsigned short* sBc = (unsigned short*)(smem + 17120);   // 4*224 us
  const int tid = threadIdx.x;
  const int wv = tid >> 6, lane = tid & 63;
  const int b = blockIdx.x * 4 + wv;

  for (int i = tid; i < 792; i += 256) sJ[i] = wsJ[i];
  #pragma unroll
  for (int r = 0; r < 16; ++r) sGc[wv * 1024 + lane * 16 + r] = 0;
  __syncthreads();

  float R[9], t[3], M[12], Jx = 0.f, Jy = 0.f, Jz = 0.f;
  const int i = lane;
  if (i < NJNT) {
    #pragma unroll
    for (int c = 0; c < 3; ++c) {
      float a = sJ[i * 3 + c];
      const float* d = sJ + 72 + (i * 3 + c) * 10;
      #pragma unroll
      for (int s = 0; s < NBETA; ++s) a += d[s] * betas[b * NBETA + s];
      if (c == 0) Jx = a; else if (c == 1) Jy = a; else Jz = a;
    }
    sJJ[wv * 72 + i * 3 + 0] = Jx;
    sJJ[wv * 72 + i * 3 + 1] = Jy;
    sJJ[wv * 72 + i * 3 + 2] = Jz;
    const float rx = thetas[b * 72 + i * 3 + 0];
    const float ry = thetas[b * 72 + i * 3 + 1];
    const float rz = thetas[b * 72 + i * 3 + 2];
    const float th = sqrtf(rx * rx + ry * ry + rz * rz) + 1e-8f;
    const float inv = 1.f / th;
    const float x = rx * inv, y = ry * inv, z = rz * inv;
    const float cs = cosf(th), sn = sinf(th), omc = 1.f - cs;
    R[0] = cs + omc*x*x;   R[1] = omc*x*y - sn*z; R[2] = omc*x*z + sn*y;
    R[3] = omc*x*y + sn*z; R[4] = cs + omc*y*y;   R[5] = omc*y*z - sn*x;
    R[6] = omc*x*z - sn*y; R[7] = omc*y*z + sn*x; R[8] = cs + omc*z*z;
    if (i == 0) {
      const float sc = scale[0];
      #pragma unroll
      for (int k = 0; k < 9; ++k) R[k] *= sc;
    } else {
      #pragma unroll
      for (int k = 0; k < 9; ++k)
        sBc[wv * 224 + (i - 1) * 9 + k] =
            f2bf(R[k] - ((k == 0 || k == 4 || k == 8) ? 1.f : 0.f));
    }
  }
  if (i == 0) {
    #pragma unroll
    for (int s = 0; s < NBETA; ++s)
      sBc[wv * 224 + NPOSE + s] = f2bf(betas[b * NBETA + s]);
    sBc[wv * 224 + NPOSE + 10] = 0x3F80;
    #pragma unroll
    for (int k = NPOSE + 11; k < KPAD; ++k) sBc[wv * 224 + k] = 0;
  }
  __syncthreads();

  if (i < NJNT) {
    if (i == 0) { t[0] = Jx; t[1] = Jy; t[2] = Jz; }
    else {
      const int p = c_par[i];
      t[0] = Jx - sJJ[wv * 72 + p * 3 + 0];
      t[1] = Jy - sJJ[wv * 72 + p * 3 + 1];
      t[2] = Jz - sJJ[wv * 72 + p * 3 + 2];
    }
    if (i == 0) {
      #pragma unroll
      for (int r = 0; r < 3; ++r) {
        M[r*4+0] = R[r*3+0]; M[r*4+1] = R[r*3+1];
        M[r*4+2] = R[r*3+2]; M[r*4+3] = t[r];
      }
      #pragma unroll
      for (int k = 0; k < 12; ++k) sM[wv * 288 + k] = M[k];
    }
  }
  __syncthreads();

  for (int lvl = 1; lvl <= 8; ++lvl) {
    if (i < NJNT && c_depth[i] == lvl) {
      const float* Mp = sM + wv * 288 + c_par[i] * 12;
      #pragma unroll
      for (int r = 0; r < 3; ++r) {
        const float p0 = Mp[r*4+0], p1 = Mp[r*4+1], p2 = Mp[r*4+2], p3 = Mp[r*4+3];
        M[r*4+0] = p0*R[0] + p1*R[3] + p2*R[6];
        M[r*4+1] = p0*R[1] + p1*R[4] + p2*R[7];
        M[r*4+2] = p0*R[2] + p1*R[5] + p2*R[8];
        M[r*4+3] = p0*t[0] + p1*t[1] + p2*t[2] + p3;
      }
      #pragma unroll
      for (int k = 0; k < 12; ++k) sM[wv * 288 + i * 12 + k] = M[k];
    }
    __syncthreads();
  }

  if (i < NJNT) {
    #pragma unroll
    for (int r = 0; r < 3; ++r) {
      M[r*4+3] = M[r*4+3] - (M[r*4+0]*Jx + M[r*4+1]*Jy + M[r*4+2]*Jz)
               + trans[b * 3 + r];
    }
    #pragma unroll
    for (int e = 0; e < 12; ++e) {
      const float g = M[e];
      const unsigned short hi = f2bf(g);
      sGc[wv * 1024 + e * 32 + i]       = hi;
      sGc[wv * 1024 + 512 + e * 32 + i] = f2bf(g - bf2f(hi));
    }
  }
  __syncthreads();

  *(uint4*)(G16 + (size_t)b * 1024 + lane * 16) =
      *(uint4*)&sGc[wv * 1024 + lane * 16];
  *(uint4*)(G16 + (size_t)b * 1024 + lane * 16 + 8) =
      *(uint4*)&sGc[wv * 1024 + lane * 16 + 8];
  if (lane < 28)
    *(uint4*)(BT + (size_t)b * KPAD + lane * 8) =
        *(uint4*)&sBc[wv * 224 + lane * 8];
}

// ---------- Phase 3: fused MFMA pose+shape GEMM + MFMA LBS (864 tiles) ----------
static __device__ __forceinline__ void phase3(
    const unsigned short* __restrict__ AT, const unsigned short* __restrict__ BT,
    const unsigned short* __restrict__ W16, const unsigned short* __restrict__ G16,
    float* __restrict__ out, char* smem) {
  unsigned short* sAs = (unsigned short*)smem;             // [192][40]
  unsigned short* sBs = (unsigned short*)(smem + 15360);   // [64][40]
  float* sV           = (float*)smem;                      // [192][17]
  unsigned short* sG2 = (unsigned short*)(smem + 13056);   // [256][40]
  unsigned short* sWh = (unsigned short*)(smem + 33536);   // [64][40]
  unsigned short* sWl = (unsigned short*)(smem + 38656);   // [64][40]

  const int tid = threadIdx.x;
  const int wv = tid >> 6, lane = tid & 63;
  const int q = lane >> 4, n = lane & 15;

  for (int tile = blockIdx.x; tile < 864; tile += gridDim.x) {
    __syncthreads();                 // protect LDS reuse across iterations
    const int b0 = (tile & 7) * 64;
    const int vty = tile >> 3;
    const int vc0 = vty * 192;

    for (int i = tid; i < 512; i += 256) {
      const int row = i >> 3, c8 = i & 7;
      const uint4 w = *(const uint4*)(W16 + (size_t)(vty * 64 + row) * 64 + c8 * 8);
      if (c8 < 4) *(uint4*)(sWh + row * 40 + c8 * 8) = w;
      else        *(uint4*)(sWl + row * 40 + (c8 - 4) * 8) = w;
    }

    floatx4 acc[3][4];
    #pragma unroll
    for (int mt = 0; mt < 3; ++mt)
      #pragma unroll
      for (int nt = 0; nt < 4; ++nt) acc[mt][nt] = (floatx4)(0.f);

    const int srow = tid >> 2, sj = tid & 3;
    for (int kt = 0; kt < 7; ++kt) {
      if (kt) __syncthreads();
      #pragma unroll
      for (int it = 0; it < 3; ++it) {
        const int row = it * 64 + srow;
        *(uint4*)(sAs + row * 40 + sj * 8) =
            *(const uint4*)(AT + (size_t)(vc0 + row) * KPAD + kt * 32 + sj * 8);
      }
      *(uint4*)(sBs + srow * 40 + sj * 8) =
          *(const uint4*)(BT + (size_t)(b0 + srow) * KPAD + kt * 32 + sj * 8);
      __syncthreads();
      short8 af[3], bfr[4];
      #pragma unroll
      for (int mt = 0; mt < 3; ++mt)
        af[mt] = *(const short8*)(sAs + (48 * wv + 16 * mt + n) * 40 + q * 8);
      #pragma unroll
      for (int nt = 0; nt < 4; ++nt)
        bfr[nt] = *(const short8*)(sBs + (16 * nt + n) * 40 + q * 8);
      #pragma unroll
      for (int mt = 0; mt < 3; ++mt)
        #pragma unroll
        for (int nt = 0; nt < 4; ++nt)
          acc[mt][nt] = __builtin_amdgcn_mfma_f32_16x16x32_bf16(
              af[mt], bfr[nt], acc[mt][nt], 0, 0, 0);
    }

    short8 wh[4], wl[4];
    #pragma unroll
    for (int vt = 0; vt < 4; ++vt) {
      wh[vt] = *(const short8*)(sWh + (vt * 16 + n) * 40 + q * 8);
      wl[vt] = *(const short8*)(sWl + (vt * 16 + n) * 40 + q * 8);
    }

    for (int nt = 0; nt < 4; ++nt) {
      for (int s = 0; s < 2; ++s) {
        __syncthreads();
        if (s == 0) {
          #pragma unroll
          for (int mt = 0; mt < 3; ++mt)
            #pragma unroll
            for (int r = 0; r < 4; ++r)
              sV[(48 * wv + 16 * mt + 4 * q + r) * 17 + n] = acc[mt][nt][r];
        }
        const int bg0 = b0 + nt * 16 + s * 8;
        for (int i = tid; i < 1024; i += 256) {
          const int row = i >> 2, c4 = i & 3;
          const int t = row >> 5, rem = row & 31;
          *(uint4*)(sG2 + row * 40 + c4 * 8) =
              *(const uint4*)(G16 + (size_t)(bg0 + t) * 1024 + rem * 32 + c4 * 8);
        }
        __syncthreads();
        #pragma unroll
        for (int bb = 0; bb < 2; ++bb) {
          const int t = wv * 2 + bb;
          const int col = s * 8 + t;
          const int bg = b0 + nt * 16 + col;
          const short8 gh = *(const short8*)(sG2 + (t * 32 + n) * 40 + q * 8);
          const short8 gl = *(const short8*)(sG2 + (t * 32 + 16 + n) * 40 + q * 8);
          #pragma unroll
          for (int vt = 0; vt < 4; ++vt) {
            floatx4 a2 = (floatx4)(0.f);
            a2 = __builtin_amdgcn_mfma_f32_16x16x32_bf16(gh, wl[vt], a2, 0, 0, 0);
            a2 = __builtin_amdgcn_mfma_f32_16x16x32_bf16(gl, wh[vt], a2, 0, 0, 0);
            a2 = __builtin_amdgcn_mfma_f32_16x16x32_bf16(gh, wh[vt], a2, 0, 0, 0);
            const float X = sV[(48 * vt + 3 * n + 0) * 17 + col];
            const float Y = sV[(48 * vt + 3 * n + 1) * 17 + col];
            const float Z = sV[(48 * vt + 3 * n + 2) * 17 + col];
            const float o = a2[0] * X + a2[1] * Y + a2[2] * Z + a2[3];
            const int vc = vc0 + 48 * vt + 3 * n + q;
            if (q < 3 && vc < NVC)
              out[(size_t)bg * NVC + vc] = o;
          }
        }
      }
    }
  }
}

// ---------- Phase 4: joints = Jr @ result ----------
static __device__ __forceinline__ void phase4(
    const float* __restrict__ Jr, float* __restrict__ out) {
  const int lane = threadIdx.x & 63, wv = threadIdx.x >> 6;
  float* jout = out + (size_t)NBATCH * NVC;
  for (int b = blockIdx.x; b < NBATCH; b += gridDim.x) {
    float jacc[18];
    #pragma unroll
    for (int k = 0; k < 18; ++k) jacc[k] = 0.f;
    const float* rb = out + (size_t)b * NVC;
    for (int v = lane; v < NVERT; v += 64) {
      const float r0 = rb[v*3+0], r1 = rb[v*3+1], r2 = rb[v*3+2];
      #pragma unroll
      for (int k = 0; k < 6; ++k) {
        const int j = wv + 4 * k;
        const float w = Jr[j * NVERT + v];
        jacc[k*3+0] += w * r0; jacc[k*3+1] += w * r1; jacc[k*3+2] += w * r2;
      }
    }
    #pragma unroll
    for (int off = 32; off > 0; off >>= 1) {
      #pragma unroll
      for (int k = 0; k < 18; ++k) jacc[k] += __shfl_down(jacc[k], off, 64);
    }
    if (lane == 0) {
      #pragma unroll
      for (int k = 0; k < 6; ++k) {
        const int j = wv + 4 * k;
        jout[(size_t)b * 72 + j * 3 + 0] = jacc[k*3+0];
        jout[(size_t)b * 72 + j * 3 + 1] = jacc[k*3+1];
        jout[(size_t)b * 72 + j * 3 + 2] = jacc[k*3+2];
      }
    }
  }
}

// ---------- cooperative monolith ----------
__global__ __launch_bounds__(256, 2) void k_mono(
    const float* __restrict__ betas, const float* __restrict__ thetas,
    const float* __restrict__ trans, const float* __restrict__ scale,
    const float* __restrict__ vtpl, const float* __restrict__ sd,
    const float* __restrict__ pdir, const float* __restrict__ Jr,
    const float* __restrict__ wgt, float* __restrict__ out,
    float* __restrict__ wsJ, unsigned short* __restrict__ AT,
    unsigned short* __restrict__ BT, unsigned short* __restrict__ W16,
    unsigned short* __restrict__ G16) {
  __shared__ __align__(16) char smem[44032];
  cg::grid_group gg = cg::this_grid();
  phase1(Jr, vtpl, sd, pdir, wgt, wsJ, AT, W16, smem);
  __threadfence(); gg.sync();
  phase2(betas, thetas, scale, trans, wsJ, BT, G16, smem);
  __threadfence(); gg.sync();
  phase3(AT, BT, W16, G16, out, smem);
  __threadfence(); gg.sync();
  phase4(Jr, out);
}

// ---------- fallback: phases as plain kernels ----------
__global__ __launch_bounds__(256, 2) void k_p1(
    const float* __restrict__ Jr, const float* __restrict__ vtpl,
    const float* __restrict__ sd, const float* __restrict__ pdir,
    const float* __restrict__ wgt, float* __restrict__ wsJ,
    unsigned short* __restrict__ AT, unsigned short* __restrict__ W16) {
  __shared__ __align__(16) char smem[192];
  phase1(Jr, vtpl, sd, pdir, wgt, wsJ, AT, W16, smem);
}
__global__ __launch_bounds__(256, 2) void k_p2(
    const float* __restrict__ betas, const float* __restrict__ thetas,
    const float* __restrict__ scale, const float* __restrict__ trans,
    const float* __restrict__ wsJ, unsigned short* __restrict__ BT,
    unsigned short* __restrict__ G16) {
  __shared__ __align__(16) char smem[18912];
  phase2(betas, thetas, scale, trans, wsJ, BT, G16, smem);
}
__global__ __launch_bounds__(256, 2) void k_p3(
    const unsigned short* __restrict__ AT, const unsigned short* __restrict__ BT,
    const unsigned short* __restrict__ W16, const unsigned short* __restrict__ G16,
    float* __restrict__ out) {
  __shared__ __align__(16) char smem[44032];
  phase3(AT, BT, W16, G16, out, smem);
}
__global__ __launch_bounds__(256, 2) void k_p4(
    const float* __restrict__ Jr, float* __restrict__ out) {
  phase4(Jr, out);
}

extern "C" void kernel_launch(void* const* d_in, const int* in_sizes, int n_in,
                              void* d_out, int out_size, void* d_ws, size_t ws_size,
                              hipStream_t stream) {
  const float* betas  = (const float*)d_in[0];
  const float* thetas = (const float*)d_in[1];
  const float* trans  = (const float*)d_in[2];
  const float* scale  = (const float*)d_in[3];
  const float* vtpl   = (const float*)d_in[4];
  const float* sd     = (const float*)d_in[5];
  const float* pdir   = (const float*)d_in[6];
  const float* Jr     = (const float*)d_in[7];
  const float* wgt    = (const float*)d_in[8];
  float* out = (float*)d_out;

  float* ws  = (float*)d_ws;
  float* wsJ = ws;                                           // 792 floats
  unsigned short* AT  = (unsigned short*)(ws + 792);         // MROWS*224
  unsigned short* BT  = AT + (size_t)MROWS * KPAD;           // 512*224
  unsigned short* W16 = BT + (size_t)NBATCH * KPAD;          // 6912*64
  unsigned short* G16 = W16 + (size_t)6912 * 64;             // 512*1024

  void* args[] = {
    (void*)&betas, (void*)&thetas, (void*)&trans, (void*)&scale,
    (void*)&vtpl, (void*)&sd, (void*)&pdir, (void*)&Jr, (void*)&wgt,
    (void*)&out, (void*)&wsJ, (void*)&AT, (void*)&BT, (void*)&W16,
    (void*)&G16
  };
  hipError_t err = hipLaunchCooperativeKernel(
      reinterpret_cast<void*>(k_mono), dim3(GRID), dim3(256), args, 0, stream);
  if (err != hipSuccess) {
    (void)hipGetLastError();   // clear sticky error, take the 4-launch path
    k_p1<<<256, 256, 0, stream>>>(Jr, vtpl, sd, pdir, wgt, wsJ, AT, W16);
    k_p2<<<128, 256, 0, stream>>>(betas, thetas, scale, trans, wsJ, BT, G16);
    k_p3<<<864, 256, 0, stream>>>(AT, BT, W16, G16, out);
    k_p4<<<512, 256, 0, stream>>>(Jr, out);
  }
}

// Round 8
// 212.046 us; speedup vs baseline: 2.1546x; 2.1546x over previous
//
#include <hip/hip_runtime.h>

#define NVERT 6890
#define NJNT  24
#define NBETA 10
#define NPOSE 207
#define NBATCH 512
#define KPAD 224          // 207 pose + 10 shape + 1 template + 6 zero
#define MROWS 20736       // 108 * 192 >= 20670
#define NVC (NVERT * 3)   // 20670

typedef __attribute__((ext_vector_type(8))) short short8;
typedef __attribute__((ext_vector_type(4))) float floatx4;

__constant__ int c_par[NJNT]   = {-1,0,0,0,1,2,3,4,5,6,7,8,9,9,9,12,13,14,16,17,18,19,20,21};
__constant__ int c_depth[NJNT] = { 0,1,1,1,2,2,2,3,3,3,4,4,4,4,4,5,5,5,6,6,7,7,8,8};

static __device__ __forceinline__ unsigned short f2bf(float x) {
  union { float f; unsigned u; } v; v.f = x;
  unsigned r = (v.u + 0x7FFFu + ((v.u >> 16) & 1u)) >> 16;
  return (unsigned short)r;
}
static __device__ __forceinline__ float bf2f(unsigned short h) {
  union { unsigned u; float f; } v; v.u = (unsigned)h << 16;
  return v.f;
}

// ---- prep: jreg (blocks<72, single-stage) + vectorized buildA/buildW ----
__global__ __launch_bounds__(256, 2) void k_prep(
    const float* __restrict__ Jr, const float* __restrict__ vtpl,
    const float* __restrict__ sd, const float* __restrict__ pdir,
    const float* __restrict__ wgt, float* __restrict__ wsJ,
    unsigned short* __restrict__ AT, unsigned short* __restrict__ W16) {
  __shared__ float red[44];
  const int tid = threadIdx.x;
  const int bid = blockIdx.x;
  const int lane = tid & 63, wv = tid >> 6;
  if (bid < 72) {
    const int j = bid / 3, c = bid - j * 3;
    float acc[11];
    #pragma unroll
    for (int k = 0; k < 11; ++k) acc[k] = 0.f;
    for (int v = tid; v < NVERT; v += 256) {
      const float w = Jr[j * NVERT + v];
      acc[0] += w * vtpl[v * 3 + c];
      const float* s = sd + (size_t)v * 30 + c * 10;
      #pragma unroll
      for (int k = 0; k < 10; ++k) acc[1 + k] += w * s[k];
    }
    #pragma unroll
    for (int off = 32; off > 0; off >>= 1) {
      #pragma unroll
      for (int k = 0; k < 11; ++k) acc[k] += __shfl_down(acc[k], off, 64);
    }
    if (lane == 0) {
      #pragma unroll
      for (int k = 0; k < 11; ++k) red[wv * 11 + k] = acc[k];
    }
    __syncthreads();
    if (tid == 0) {
      #pragma unroll
      for (int k = 0; k < 11; ++k) {
        const float s = red[k] + red[11 + k] + red[22 + k] + red[33 + k];
        if (k == 0) wsJ[bid] = s;
        else        wsJ[72 + bid * 10 + (k - 1)] = s;
      }
    }
  }
  const int gid = bid * 256 + tid;
  const int gstride = gridDim.x * 256;
  for (int u = gid; u < MROWS * KPAD / 8; u += gstride) {     // buildA
    const int row = u / 28, k0 = (u - row * 28) * 8;
    short8 r;
    #pragma unroll
    for (int e = 0; e < 8; ++e) {
      const int k = k0 + e;
      float val = 0.f;
      if (row < NVC) {
        if (k < NPOSE)            val = pdir[(size_t)row * NPOSE + k];
        else if (k < NPOSE + 10)  val = sd[(size_t)row * 10 + (k - NPOSE)];
        else if (k == NPOSE + 10) val = vtpl[row];
      }
      r[e] = (short)f2bf(val);
    }
    *(short8*)(AT + (size_t)u * 8) = r;
  }
  for (int u = gid; u < 6912 * 64 / 8; u += gstride) {        // buildW
    const int v = u >> 3, c0 = (u & 7) * 8;
    short8 r;
    #pragma unroll
    for (int e = 0; e < 8; ++e) {
      const int c = c0 + e, j = c & 31;
      const float w = (v < NVERT && j < 24) ? wgt[(size_t)v * 24 + j] : 0.f;
      const unsigned short hi = f2bf(w);
      r[e] = (short)((c >> 5) ? f2bf(w - bf2f(hi)) : hi);
    }
    *(short8*)(W16 + (size_t)u * 8) = r;
  }
}

// ---- chain: 128 blocks, wave=batch, tree-level parallel -> BT, G16 ----
__global__ __launch_bounds__(256, 2) void k_chain(
    const float* __restrict__ betas, const float* __restrict__ thetas,
    const float* __restrict__ scale, const float* __restrict__ trans,
    const float* __restrict__ wsJ,
    unsigned short* __restrict__ BT, unsigned short* __restrict__ G16) {
  __shared__ __align__(16) float sJ[792];
  __shared__ __align__(16) float sJJ[4][72];
  __shared__ __align__(16) float sM[4][288];
  __shared__ __align__(16) unsigned short sGc[4][1024];
  __shared__ __align__(16) unsigned short sBc[4][KPAD];
  const int tid = threadIdx.x;
  const int wv = tid >> 6, lane = tid & 63;
  const int b = blockIdx.x * 4 + wv;

  for (int i = tid; i < 792; i += 256) sJ[i] = wsJ[i];
  #pragma unroll
  for (int r = 0; r < 16; ++r) sGc[wv][lane * 16 + r] = 0;
  __syncthreads();

  float R[9], t[3], M[12], Jx = 0.f, Jy = 0.f, Jz = 0.f;
  const int i = lane;
  if (i < NJNT) {
    #pragma unroll
    for (int c = 0; c < 3; ++c) {
      float a = sJ[i * 3 + c];
      const float* d = sJ + 72 + (i * 3 + c) * 10;
      #pragma unroll
      for (int s = 0; s < NBETA; ++s) a += d[s] * betas[b * NBETA + s];
      if (c == 0) Jx = a; else if (c == 1) Jy = a; else Jz = a;
    }
    sJJ[wv][i * 3 + 0] = Jx; sJJ[wv][i * 3 + 1] = Jy; sJJ[wv][i * 3 + 2] = Jz;
    const float rx = thetas[b * 72 + i * 3 + 0];
    const float ry = thetas[b * 72 + i * 3 + 1];
    const float rz = thetas[b * 72 + i * 3 + 2];
    const float th = sqrtf(rx * rx + ry * ry + rz * rz) + 1e-8f;
    const float inv = 1.f / th;
    const float x = rx * inv, y = ry * inv, z = rz * inv;
    const float cs = cosf(th), sn = sinf(th), omc = 1.f - cs;
    R[0] = cs + omc*x*x;   R[1] = omc*x*y - sn*z; R[2] = omc*x*z + sn*y;
    R[3] = omc*x*y + sn*z; R[4] = cs + omc*y*y;   R[5] = omc*y*z - sn*x;
    R[6] = omc*x*z - sn*y; R[7] = omc*y*z + sn*x; R[8] = cs + omc*z*z;
    if (i == 0) {
      const float sc = scale[0];
      #pragma unroll
      for (int k = 0; k < 9; ++k) R[k] *= sc;
    } else {
      #pragma unroll
      for (int k = 0; k < 9; ++k)
        sBc[wv][(i - 1) * 9 + k] =
            f2bf(R[k] - ((k == 0 || k == 4 || k == 8) ? 1.f : 0.f));
    }
  }
  if (i == 0) {
    #pragma unroll
    for (int s = 0; s < NBETA; ++s)
      sBc[wv][NPOSE + s] = f2bf(betas[b * NBETA + s]);
    sBc[wv][NPOSE + 10] = 0x3F80;
    #pragma unroll
    for (int k = NPOSE + 11; k < KPAD; ++k) sBc[wv][k] = 0;
  }
  __syncthreads();

  if (i < NJNT) {
    if (i == 0) { t[0] = Jx; t[1] = Jy; t[2] = Jz; }
    else {
      const int p = c_par[i];
      t[0] = Jx - sJJ[wv][p * 3 + 0];
      t[1] = Jy - sJJ[wv][p * 3 + 1];
      t[2] = Jz - sJJ[wv][p * 3 + 2];
    }
    if (i == 0) {
      #pragma unroll
      for (int r = 0; r < 3; ++r) {
        M[r*4+0] = R[r*3+0]; M[r*4+1] = R[r*3+1];
        M[r*4+2] = R[r*3+2]; M[r*4+3] = t[r];
      }
      #pragma unroll
      for (int k = 0; k < 12; ++k) sM[wv][k] = M[k];
    }
  }
  __syncthreads();

  for (int lvl = 1; lvl <= 8; ++lvl) {
    if (i < NJNT && c_depth[i] == lvl) {
      const float* Mp = sM[wv] + c_par[i] * 12;
      #pragma unroll
      for (int r = 0; r < 3; ++r) {
        const float p0 = Mp[r*4+0], p1 = Mp[r*4+1], p2 = Mp[r*4+2], p3 = Mp[r*4+3];
        M[r*4+0] = p0*R[0] + p1*R[3] + p2*R[6];
        M[r*4+1] = p0*R[1] + p1*R[4] + p2*R[7];
        M[r*4+2] = p0*R[2] + p1*R[5] + p2*R[8];
        M[r*4+3] = p0*t[0] + p1*t[1] + p2*t[2] + p3;
      }
      #pragma unroll
      for (int k = 0; k < 12; ++k) sM[wv][i * 12 + k] = M[k];
    }
    __syncthreads();
  }

  if (i < NJNT) {
    #pragma unroll
    for (int r = 0; r < 3; ++r) {
      M[r*4+3] = M[r*4+3] - (M[r*4+0]*Jx + M[r*4+1]*Jy + M[r*4+2]*Jz)
               + trans[b * 3 + r];
    }
    #pragma unroll
    for (int e = 0; e < 12; ++e) {
      const float g = M[e];
      const unsigned short hi = f2bf(g);
      sGc[wv][e * 32 + i]       = hi;
      sGc[wv][512 + e * 32 + i] = f2bf(g - bf2f(hi));
    }
  }
  __syncthreads();

  *(uint4*)(G16 + (size_t)b * 1024 + lane * 16)     = *(uint4*)&sGc[wv][lane * 16];
  *(uint4*)(G16 + (size_t)b * 1024 + lane * 16 + 8) = *(uint4*)&sGc[wv][lane * 16 + 8];
  if (lane < 28)
    *(uint4*)(BT + (size_t)b * KPAD + lane * 8) = *(uint4*)&sBc[wv][lane * 8];
}

// ---- fused MFMA pose+shape GEMM + MFMA LBS. block: 192 vc x 64 batches ----
__global__ __launch_bounds__(256, 3) void k_skin(
    const unsigned short* __restrict__ AT, const unsigned short* __restrict__ BT,
    const unsigned short* __restrict__ W16, const unsigned short* __restrict__ G16,
    float* __restrict__ out) {
  __shared__ __align__(16) char smem[43776];
  unsigned short* sAs = (unsigned short*)smem;             // [192][40] GEMM A
  unsigned short* sBs = (unsigned short*)(smem + 15360);   // [64][40]  GEMM B
  float* sV           = (float*)smem;                      // [192][17] epi: vph
  unsigned short* sG2 = (unsigned short*)(smem + 13056);   // [256][40] epi: G hi/lo
  unsigned short* sWh = (unsigned short*)(smem + 33536);   // [64][40]  W hi
  unsigned short* sWl = (unsigned short*)(smem + 38656);   // [64][40]  W lo

  const int tid = threadIdx.x;
  const int wv = tid >> 6, lane = tid & 63;
  const int q = lane >> 4, n = lane & 15;
  const int b0 = blockIdx.x * 64;
  const int vc0 = blockIdx.y * 192;

  for (int i = tid; i < 512; i += 256) {
    const int row = i >> 3, c8 = i & 7;
    const uint4 w = *(const uint4*)(W16 + (size_t)(blockIdx.y * 64 + row) * 64 + c8 * 8);
    if (c8 < 4) *(uint4*)(sWh + row * 40 + c8 * 8) = w;
    else        *(uint4*)(sWl + row * 40 + (c8 - 4) * 8) = w;
  }

  floatx4 acc[3][4];
  #pragma unroll
  for (int mt = 0; mt < 3; ++mt)
    #pragma unroll
    for (int nt = 0; nt < 4; ++nt) acc[mt][nt] = (floatx4)(0.f);

  const int srow = tid >> 2, sj = tid & 3;
  for (int kt = 0; kt < 7; ++kt) {
    if (kt) __syncthreads();
    #pragma unroll
    for (int it = 0; it < 3; ++it) {
      const int row = it * 64 + srow;
      *(uint4*)(sAs + row * 40 + sj * 8) =
          *(const uint4*)(AT + (size_t)(vc0 + row) * KPAD + kt * 32 + sj * 8);
    }
    *(uint4*)(sBs + srow * 40 + sj * 8) =
        *(const uint4*)(BT + (size_t)(b0 + srow) * KPAD + kt * 32 + sj * 8);
    __syncthreads();
    short8 af[3], bfr[4];
    #pragma unroll
    for (int mt = 0; mt < 3; ++mt)
      af[mt] = *(const short8*)(sAs + (48 * wv + 16 * mt + n) * 40 + q * 8);
    #pragma unroll
    for (int nt = 0; nt < 4; ++nt)
      bfr[nt] = *(const short8*)(sBs + (16 * nt + n) * 40 + q * 8);
    #pragma unroll
    for (int mt = 0; mt < 3; ++mt)
      #pragma unroll
      for (int nt = 0; nt < 4; ++nt)
        acc[mt][nt] = __builtin_amdgcn_mfma_f32_16x16x32_bf16(
            af[mt], bfr[nt], acc[mt][nt], 0, 0, 0);
  }

  short8 wh[4], wl[4];
  #pragma unroll
  for (int vt = 0; vt < 4; ++vt) {
    wh[vt] = *(const short8*)(sWh + (vt * 16 + n) * 40 + q * 8);
    wl[vt] = *(const short8*)(sWl + (vt * 16 + n) * 40 + q * 8);
  }

  for (int nt = 0; nt < 4; ++nt) {
    for (int s = 0; s < 2; ++s) {
      __syncthreads();
      if (s == 0) {
        #pragma unroll
        for (int mt = 0; mt < 3; ++mt)
          #pragma unroll
          for (int r = 0; r < 4; ++r)
            sV[(48 * wv + 16 * mt + 4 * q + r) * 17 + n] = acc[mt][nt][r];
      }
      const int bg0 = b0 + nt * 16 + s * 8;
      for (int i = tid; i < 1024; i += 256) {
        const int row = i >> 2, c4 = i & 3;
        const int t = row >> 5, rem = row & 31;
        *(uint4*)(sG2 + row * 40 + c4 * 8) =
            *(const uint4*)(G16 + (size_t)(bg0 + t) * 1024 + rem * 32 + c4 * 8);
      }
      __syncthreads();
      #pragma unroll
      for (int bb = 0; bb < 2; ++bb) {
        const int t = wv * 2 + bb;
        const int col = s * 8 + t;
        const int bg = b0 + nt * 16 + col;
        const short8 gh = *(const short8*)(sG2 + (t * 32 + n) * 40 + q * 8);
        const short8 gl = *(const short8*)(sG2 + (t * 32 + 16 + n) * 40 + q * 8);
        #pragma unroll
        for (int vt = 0; vt < 4; ++vt) {
          floatx4 a2 = (floatx4)(0.f);
          a2 = __builtin_amdgcn_mfma_f32_16x16x32_bf16(gh, wl[vt], a2, 0, 0, 0);
          a2 = __builtin_amdgcn_mfma_f32_16x16x32_bf16(gl, wh[vt], a2, 0, 0, 0);
          a2 = __builtin_amdgcn_mfma_f32_16x16x32_bf16(gh, wh[vt], a2, 0, 0, 0);
          const float X = sV[(48 * vt + 3 * n + 0) * 17 + col];
          const float Y = sV[(48 * vt + 3 * n + 1) * 17 + col];
          const float Z = sV[(48 * vt + 3 * n + 2) * 17 + col];
          const float o = a2[0] * X + a2[1] * Y + a2[2] * Z + a2[3];
          const int vc = vc0 + 48 * vt + 3 * n + q;
          if (q < 3 && vc < NVC)
            out[(size_t)bg * NVC + vc] = o;
        }
      }
    }
  }
}

// ---- joints = Jr @ result ----
__global__ __launch_bounds__(256) void k_joints(
    const float* __restrict__ Jr, const float* __restrict__ res,
    float* __restrict__ joints) {
  const int b = blockIdx.x;
  const int lane = threadIdx.x & 63, wv = threadIdx.x >> 6;
  float acc[18];
  #pragma unroll
  for (int k = 0; k < 18; ++k) acc[k] = 0.f;
  const float* rb = res + (size_t)b * NVC;
  for (int v = lane; v < NVERT; v += 64) {
    const float r0 = rb[v*3+0], r1 = rb[v*3+1], r2 = rb[v*3+2];
    #pragma unroll
    for (int k = 0; k < 6; ++k) {
      const int j = wv + 4 * k;
      const float w = Jr[j * NVERT + v];
      acc[k*3+0] += w * r0; acc[k*3+1] += w * r1; acc[k*3+2] += w * r2;
    }
  }
  #pragma unroll
  for (int off = 32; off > 0; off >>= 1) {
    #pragma unroll
    for (int k = 0; k < 18; ++k) acc[k] += __shfl_down(acc[k], off, 64);
  }
  if (lane == 0) {
    #pragma unroll
    for (int k = 0; k < 6; ++k) {
      const int j = wv + 4 * k;
      joints[(size_t)b * 72 + j * 3 + 0] = acc[k*3+0];
      joints[(size_t)b * 72 + j * 3 + 1] = acc[k*3+1];
      joints[(size_t)b * 72 + j * 3 + 2] = acc[k*3+2];
    }
  }
}

extern "C" void kernel_launch(void* const* d_in, const int* in_sizes, int n_in,
                              void* d_out, int out_size, void* d_ws, size_t ws_size,
                              hipStream_t stream) {
  const float* betas  = (const float*)d_in[0];
  const float* thetas = (const float*)d_in[1];
  const float* trans  = (const float*)d_in[2];
  const float* scale  = (const float*)d_in[3];
  const float* vtpl   = (const float*)d_in[4];
  const float* sd     = (const float*)d_in[5];
  const float* pdir   = (const float*)d_in[6];
  const float* Jr     = (const float*)d_in[7];
  const float* wgt    = (const float*)d_in[8];
  float* out = (float*)d_out;

  float* ws  = (float*)d_ws;
  float* wsJ = ws;                                           // 792 floats
  unsigned short* AT  = (unsigned short*)(ws + 792);         // MROWS*224
  unsigned short* BT  = AT + (size_t)MROWS * KPAD;           // 512*224
  unsigned short* W16 = BT + (size_t)NBATCH * KPAD;          // 6912*64
  unsigned short* G16 = W16 + (size_t)6912 * 64;             // 512*1024

  k_prep<<<648, 256, 0, stream>>>(Jr, vtpl, sd, pdir, wgt, wsJ, AT, W16);
  k_chain<<<NBATCH / 4, 256, 0, stream>>>(betas, thetas, scale, trans, wsJ, BT, G16);
  k_skin<<<dim3(8, 108), 256, 0, stream>>>(AT, BT, W16, G16, out);
  k_joints<<<NBATCH, 256, 0, stream>>>(Jr, out, out + (size_t)NBATCH * NVC);
}